// Round 1
// baseline (581.344 us; speedup 1.0000x reference)
//
#include <hip/hip_runtime.h>
#include <math.h>

// ---------------------------------------------------------------------------
// GAT 2-layer forward. N=50000, E=1.6M (+N self loops), F: 128 -> (4x32) -> 64.
// Strategy: build dst-CSR once (histogram/scan/scatter), then per layer:
//   GEMM (fp32 register-tiled) -> per-node attention dots -> one wave per dst
//   node doing segment softmax + weighted gather-accumulate in registers.
// ---------------------------------------------------------------------------

__global__ __launch_bounds__(256) void hist_kernel(const int* __restrict__ eidx,
        int* __restrict__ cnt, int E, int etot)
{
    int i = blockIdx.x * 256 + threadIdx.x;
    if (i >= etot) return;
    int dst = (i < E) ? eidx[E + i] : (i - E);   // self loop dst = i-E
    atomicAdd(&cnt[dst], 1);
}

__global__ __launch_bounds__(256) void scan_block_kernel(const int* __restrict__ cnt,
        int* __restrict__ pre, int* __restrict__ bsums, int n)
{
    __shared__ int sd[256];
    int t = threadIdx.x;
    int base = blockIdx.x * 1024 + t * 4;
    int v0 = 0, v1 = 0, v2 = 0, v3 = 0;
    if (base + 0 < n) v0 = cnt[base + 0];
    if (base + 1 < n) v1 = cnt[base + 1];
    if (base + 2 < n) v2 = cnt[base + 2];
    if (base + 3 < n) v3 = cnt[base + 3];
    int s = v0 + v1 + v2 + v3;
    sd[t] = s;
    __syncthreads();
    for (int off = 1; off < 256; off <<= 1) {
        int y = (t >= off) ? sd[t - off] : 0;
        __syncthreads();
        sd[t] += y;
        __syncthreads();
    }
    int excl = sd[t] - s;
    if (base + 0 < n) pre[base + 0] = excl; excl += v0;
    if (base + 1 < n) pre[base + 1] = excl; excl += v1;
    if (base + 2 < n) pre[base + 2] = excl; excl += v2;
    if (base + 3 < n) pre[base + 3] = excl;
    if (t == 255) bsums[blockIdx.x] = sd[255];
}

__global__ __launch_bounds__(64) void scan_tops_kernel(int* bsums, int nb)
{
    int lane = threadIdx.x;
    int v = (lane < nb) ? bsums[lane] : 0;
    int x = v;
    #pragma unroll
    for (int off = 1; off < 64; off <<= 1) {
        int y = __shfl_up(x, off);
        if (lane >= off) x += y;
    }
    if (lane < nb) bsums[lane] = x - v;  // exclusive
}

// pre may alias fill (read-then-write same index in same thread: safe)
__global__ __launch_bounds__(256) void scan_finalize_kernel(const int* pre,
        const int* __restrict__ bsums, int* __restrict__ row_ptr, int* fill,
        int n, int etot)
{
    int idx = blockIdx.x * 256 + threadIdx.x;
    if (idx < n) {
        int val = pre[idx] + bsums[idx >> 10];
        row_ptr[idx] = val;
        fill[idx] = val;
    }
    if (idx == 0) row_ptr[n] = etot;
}

__global__ __launch_bounds__(256) void scatter_kernel(const int* __restrict__ eidx,
        int* __restrict__ fill, int* __restrict__ col, int E, int etot)
{
    int i = blockIdx.x * 256 + threadIdx.x;
    if (i >= etot) return;
    int src, dst;
    if (i < E) { src = eidx[i]; dst = eidx[E + i]; }
    else       { src = i - E;  dst = i - E; }
    int pos = atomicAdd(&fill[dst], 1);
    col[pos] = src;
}

// ---------------------------------------------------------------------------
// GEMM: Y[M,NOUT] = X[M,128] @ W[128,NOUT]. 4 rows x 4 cols per thread.
// ---------------------------------------------------------------------------
#define FMA4(A, S, WV) { A.x += (S)*(WV).x; A.y += (S)*(WV).y; A.z += (S)*(WV).z; A.w += (S)*(WV).w; }

template<int NOUT>
__global__ __launch_bounds__(256) void gemm_kernel(const float* __restrict__ X,
        const float* __restrict__ W, float* __restrict__ Y, int M)
{
    constexpr int CG = NOUT / 4;       // col groups per row
    constexpr int TR = (256 / CG) * 4; // rows per block (32 for 128, 64 for 64)
    int tid = threadIdx.x;
    int cx = tid % CG;
    int ry = tid / CG;
    int r0 = blockIdx.x * TR + ry * 4;
    int c0 = cx * 4;
    float4 acc0 = {0,0,0,0}, acc1 = {0,0,0,0}, acc2 = {0,0,0,0}, acc3 = {0,0,0,0};
    int r[4];
    #pragma unroll
    for (int i = 0; i < 4; i++) { r[i] = r0 + i; if (r[i] > M - 1) r[i] = M - 1; }
    for (int k = 0; k < 128; k += 4) {
        float4 x0 = *(const float4*)(X + (size_t)r[0] * 128 + k);
        float4 x1 = *(const float4*)(X + (size_t)r[1] * 128 + k);
        float4 x2 = *(const float4*)(X + (size_t)r[2] * 128 + k);
        float4 x3 = *(const float4*)(X + (size_t)r[3] * 128 + k);
        float4 w0 = *(const float4*)(W + (size_t)(k + 0) * NOUT + c0);
        float4 w1 = *(const float4*)(W + (size_t)(k + 1) * NOUT + c0);
        float4 w2 = *(const float4*)(W + (size_t)(k + 2) * NOUT + c0);
        float4 w3 = *(const float4*)(W + (size_t)(k + 3) * NOUT + c0);
        FMA4(acc0, x0.x, w0) FMA4(acc0, x0.y, w1) FMA4(acc0, x0.z, w2) FMA4(acc0, x0.w, w3)
        FMA4(acc1, x1.x, w0) FMA4(acc1, x1.y, w1) FMA4(acc1, x1.z, w2) FMA4(acc1, x1.w, w3)
        FMA4(acc2, x2.x, w0) FMA4(acc2, x2.y, w1) FMA4(acc2, x2.z, w2) FMA4(acc2, x2.w, w3)
        FMA4(acc3, x3.x, w0) FMA4(acc3, x3.y, w1) FMA4(acc3, x3.z, w2) FMA4(acc3, x3.w, w3)
    }
    if (r0 + 0 < M) *(float4*)(Y + (size_t)(r0 + 0) * NOUT + c0) = acc0;
    if (r0 + 1 < M) *(float4*)(Y + (size_t)(r0 + 1) * NOUT + c0) = acc1;
    if (r0 + 2 < M) *(float4*)(Y + (size_t)(r0 + 2) * NOUT + c0) = acc2;
    if (r0 + 3 < M) *(float4*)(Y + (size_t)(r0 + 3) * NOUT + c0) = acc3;
}

// ---------------------------------------------------------------------------
// Per-node attention dot products: a_src[n,h] = <h[n,h,:], att_src[h,:]>.
// One wave per node.
// ---------------------------------------------------------------------------
template<int H, int C>
__global__ __launch_bounds__(256) void attn_kernel(const float* __restrict__ Hf,
        const float* __restrict__ att_s, const float* __restrict__ att_d,
        float* __restrict__ as_, float* __restrict__ ad_, int M)
{
    constexpr int D = H * C, VPL = D / 64, GRP = C / VPL;
    int wave = threadIdx.x >> 6, lane = threadIdx.x & 63;
    int node = blockIdx.x * 4 + wave;
    if (node >= M) return;
    float ps = 0.f, pd = 0.f;
    #pragma unroll
    for (int v = 0; v < VPL; v++) {
        int ch = lane * VPL + v;
        float hv = Hf[(size_t)node * D + ch];
        ps += hv * att_s[ch];
        pd += hv * att_d[ch];
    }
    #pragma unroll
    for (int off = GRP / 2; off >= 1; off >>= 1) {
        ps += __shfl_xor(ps, off);
        pd += __shfl_xor(pd, off);
    }
    if ((lane & (GRP - 1)) == 0) {
        int h = lane / GRP;
        as_[node * H + h] = ps;
        ad_[node * H + h] = pd;
    }
}

// ---------------------------------------------------------------------------
// Segment softmax + aggregate, one wave per destination node.
// LPE lanes cover one edge's D channels (float4/lane); EPI edges per iter.
// ---------------------------------------------------------------------------
template<int H, int C, bool ELU>
__global__ __launch_bounds__(256) void aggregate_kernel(
        const int* __restrict__ row_ptr, const int* __restrict__ col_src,
        const float* __restrict__ Hf, const float* __restrict__ asv,
        const float* __restrict__ adv, const float* __restrict__ bias,
        float* __restrict__ out, int nnodes)
{
    constexpr int D = H * C;
    constexpr int LPE = D / 4;     // lanes per edge (32 or 16)
    constexpr int EPI = 64 / LPE;  // edges per iteration (2 or 4)
    int wave = threadIdx.x >> 6, lane = threadIdx.x & 63;
    int node = blockIdx.x * 4 + wave;
    if (node >= nnodes) return;
    int start = row_ptr[node];
    int deg   = row_ptr[node + 1] - start;
    int li  = lane & (LPE - 1);
    int sub = lane / LPE;
    int my_head = (li * 4) / C;

    float adh[H];
    #pragma unroll
    for (int h = 0; h < H; h++) adh[h] = adv[node * H + h];

    // ---- pass A: segment max per head ----
    float m[H];
    #pragma unroll
    for (int h = 0; h < H; h++) m[h] = -3.0e38f;
    for (int c0 = 0; c0 < deg; c0 += 64) {
        int idx = c0 + lane;
        float e[H];
        if (idx < deg) {
            int s = col_src[start + idx];
            if constexpr (H == 4) {
                float4 av = *(const float4*)(asv + (size_t)s * 4);
                float t0 = av.x + adh[0], t1 = av.y + adh[1];
                float t2 = av.z + adh[2], t3 = av.w + adh[3];
                e[0] = fmaxf(t0, 0.2f * t0); e[1] = fmaxf(t1, 0.2f * t1);
                e[2] = fmaxf(t2, 0.2f * t2); e[3] = fmaxf(t3, 0.2f * t3);
            } else {
                #pragma unroll
                for (int h = 0; h < H; h++) {
                    float t = asv[(size_t)s * H + h] + adh[h];
                    e[h] = fmaxf(t, 0.2f * t);
                }
            }
        } else {
            #pragma unroll
            for (int h = 0; h < H; h++) e[h] = -3.0e38f;
        }
        #pragma unroll
        for (int h = 0; h < H; h++) {
            float v = e[h];
            #pragma unroll
            for (int off = 32; off >= 1; off >>= 1)
                v = fmaxf(v, __shfl_xor(v, off));
            m[h] = fmaxf(m[h], v);
        }
    }
    float mh = m[my_head];

    // ---- pass B: exp, sum, weighted accumulate ----
    float4 acc = {0.f, 0.f, 0.f, 0.f};
    float sacc = 0.f;
    for (int c0 = 0; c0 < deg; c0 += 64) {
        int cnt = deg - c0; if (cnt > 64) cnt = 64;
        int idx = c0 + lane;
        int svec = 0;
        float exv[H];
        #pragma unroll
        for (int h = 0; h < H; h++) exv[h] = 0.f;
        if (idx < deg) {
            svec = col_src[start + idx];
            if constexpr (H == 4) {
                float4 av = *(const float4*)(asv + (size_t)svec * 4);
                float t0 = av.x + adh[0], t1 = av.y + adh[1];
                float t2 = av.z + adh[2], t3 = av.w + adh[3];
                t0 = fmaxf(t0, 0.2f * t0); t1 = fmaxf(t1, 0.2f * t1);
                t2 = fmaxf(t2, 0.2f * t2); t3 = fmaxf(t3, 0.2f * t3);
                exv[0] = __expf(t0 - m[0]); exv[1] = __expf(t1 - m[1]);
                exv[2] = __expf(t2 - m[2]); exv[3] = __expf(t3 - m[3]);
            } else {
                #pragma unroll
                for (int h = 0; h < H; h++) {
                    float t = asv[(size_t)svec * H + h] + adh[h];
                    t = fmaxf(t, 0.2f * t);
                    exv[h] = __expf(t - m[h]);
                }
            }
        }
        for (int j = 0; j < cnt; j += EPI) {
            int el = j + sub;
            bool valid = (el < cnt);
            if (el > cnt - 1) el = cnt - 1;
            int sj = __shfl(svec, el);
            float exj;
            if constexpr (H == 4) {
                float v0 = __shfl(exv[0], el), v1 = __shfl(exv[1], el);
                float v2 = __shfl(exv[2], el), v3 = __shfl(exv[3], el);
                exj = (my_head == 0) ? v0 : ((my_head == 1) ? v1 : ((my_head == 2) ? v2 : v3));
            } else {
                exj = __shfl(exv[0], el);
            }
            if (!valid) exj = 0.f;
            sacc += exj;
            const float4 hv = *(const float4*)(Hf + (size_t)sj * D + li * 4);
            acc.x += exj * hv.x; acc.y += exj * hv.y;
            acc.z += exj * hv.z; acc.w += exj * hv.w;
        }
    }

    // reduce over the EPI edge-slots (lanes with identical li)
    #pragma unroll
    for (int off = LPE; off < 64; off <<= 1) {
        sacc  += __shfl_xor(sacc, off);
        acc.x += __shfl_xor(acc.x, off);
        acc.y += __shfl_xor(acc.y, off);
        acc.z += __shfl_xor(acc.z, off);
        acc.w += __shfl_xor(acc.w, off);
    }
    if (sub == 0) {
        float inv = 1.f / (sacc + 1e-16f);
        int ch = li * 4;
        float4 r;
        r.x = acc.x * inv + bias[ch + 0];
        r.y = acc.y * inv + bias[ch + 1];
        r.z = acc.z * inv + bias[ch + 2];
        r.w = acc.w * inv + bias[ch + 3];
        if (ELU) {
            r.x = r.x > 0.f ? r.x : (__expf(r.x) - 1.f);
            r.y = r.y > 0.f ? r.y : (__expf(r.y) - 1.f);
            r.z = r.z > 0.f ? r.z : (__expf(r.z) - 1.f);
            r.w = r.w > 0.f ? r.w : (__expf(r.w) - 1.f);
        }
        *(float4*)(out + (size_t)node * D + ch) = r;
    }
}

// ---------------------------------------------------------------------------
extern "C" void kernel_launch(void* const* d_in, const int* in_sizes, int n_in,
                              void* d_out, int out_size, void* d_ws, size_t ws_size,
                              hipStream_t stream)
{
    const float* x        = (const float*)d_in[0];
    const int*   eidx     = (const int*)  d_in[1];
    const float* W1       = (const float*)d_in[2];
    const float* att_src1 = (const float*)d_in[3];
    const float* att_dst1 = (const float*)d_in[4];
    const float* bias1    = (const float*)d_in[5];
    const float* W2       = (const float*)d_in[6];
    const float* att_src2 = (const float*)d_in[7];
    const float* att_dst2 = (const float*)d_in[8];
    const float* bias2    = (const float*)d_in[9];
    float* out = (float*)d_out;

    const int N_ = in_sizes[0] / 128;
    const int E_ = in_sizes[1] / 2;
    const int ET = E_ + N_;

    char* p = (char*)d_ws;
    auto alloc = [&](size_t bytes) {
        void* r = (void*)p;
        p += ((bytes + 255) / 256) * 256;
        return r;
    };
    int*   cnt   = (int*)  alloc((size_t)N_ * 4);
    int*   rowp  = (int*)  alloc((size_t)(N_ + 1) * 4);
    int*   fill  = (int*)  alloc((size_t)N_ * 4);
    int*   bsums = (int*)  alloc(64 * 4);
    int*   col   = (int*)  alloc((size_t)ET * 4);
    float* h1    = (float*)alloc((size_t)N_ * 128 * 4);
    float* hx    = (float*)alloc((size_t)N_ * 128 * 4);
    float* h2    = (float*)alloc((size_t)N_ * 64 * 4);
    float* as1   = (float*)alloc((size_t)N_ * 4 * 4);
    float* ad1   = (float*)alloc((size_t)N_ * 4 * 4);
    float* as2   = (float*)alloc((size_t)N_ * 4);
    float* ad2   = (float*)alloc((size_t)N_ * 4);
    (void)ws_size; (void)n_in; (void)out_size;

    // ---- build dst-CSR ----
    hipMemsetAsync(cnt, 0, (size_t)N_ * 4, stream);
    hist_kernel<<<(ET + 255) / 256, 256, 0, stream>>>(eidx, cnt, E_, ET);
    int nb = (N_ + 1023) / 1024;
    scan_block_kernel<<<nb, 256, 0, stream>>>(cnt, fill, bsums, N_);
    scan_tops_kernel<<<1, 64, 0, stream>>>(bsums, nb);
    scan_finalize_kernel<<<(N_ + 255) / 256, 256, 0, stream>>>(fill, bsums, rowp, fill, N_, ET);
    scatter_kernel<<<(ET + 255) / 256, 256, 0, stream>>>(eidx, fill, col, E_, ET);

    // ---- layer 1: H=4, C=32 ----
    gemm_kernel<128><<<(N_ + 31) / 32, 256, 0, stream>>>(x, W1, h1, N_);
    attn_kernel<4, 32><<<(N_ + 3) / 4, 256, 0, stream>>>(h1, att_src1, att_dst1, as1, ad1, N_);
    aggregate_kernel<4, 32, true><<<(N_ + 3) / 4, 256, 0, stream>>>(rowp, col, h1, as1, ad1, bias1, hx, N_);

    // ---- layer 2: H=1, C=64 ----
    gemm_kernel<64><<<(N_ + 63) / 64, 256, 0, stream>>>(hx, W2, h2, N_);
    attn_kernel<1, 64><<<(N_ + 3) / 4, 256, 0, stream>>>(h2, att_src2, att_dst2, as2, ad2, N_);
    aggregate_kernel<1, 64, false><<<(N_ + 3) / 4, 256, 0, stream>>>(rowp, col, h2, as2, ad2, bias2, out, N_);
}

// Round 2
// 408.427 us; speedup vs baseline: 1.4234x; 1.4234x over previous
//
#include <hip/hip_runtime.h>
#include <math.h>

// ---------------------------------------------------------------------------
// GAT 2-layer forward. N=50000, E=1.6M (+N self loops), F: 128 -> (4x32) -> 64.
// CSR build: locality-aware two-pass bucket sort of packed (dst<<16|src) codes
// (replaces atomic scatter that caused 15x HBM write amplification, R1).
// Then per layer: fp32 register-tiled GEMM -> per-node attention dots ->
// one wave per dst node doing segment softmax + gather-accumulate.
// ---------------------------------------------------------------------------

#define NB_BUCKETS 256   // max coarse buckets (dst>>8); actual used = ceil(N/256)
#define BCAP 16384       // fixed capacity per coarse bucket region (avg ~8448)

// ---- pass A: block-aggregated split into coarse buckets by dst>>8 ----------
__global__ __launch_bounds__(256) void splitA_kernel(const int* __restrict__ eidx,
        unsigned int* __restrict__ tmp, int* __restrict__ coarse_fill,
        int E, int etot, int nb)
{
    __shared__ int hist[NB_BUCKETS];
    __shared__ int gb[NB_BUCKETS];
    __shared__ int cnt2[NB_BUCKETS];
    int t = threadIdx.x;
    if (t < nb) { hist[t] = 0; cnt2[t] = 0; }
    __syncthreads();

    unsigned int val[16];
    int bkt[16];
    int base = blockIdx.x * 4096;
    #pragma unroll
    for (int i = 0; i < 16; i++) {
        int idx = base + i * 256 + t;
        if (idx < etot) {
            unsigned int s, d;
            if (idx < E) { s = (unsigned int)eidx[idx]; d = (unsigned int)eidx[E + idx]; }
            else         { s = (unsigned int)(idx - E); d = s; }
            val[i] = (d << 16) | s;
            bkt[i] = (int)(d >> 8);
            atomicAdd(&hist[bkt[i]], 1);
        } else {
            bkt[i] = -1;
        }
    }
    __syncthreads();
    if (t < nb) {
        int n = hist[t];
        gb[t] = (n > 0) ? atomicAdd(&coarse_fill[t], n) : 0;
    }
    __syncthreads();
    #pragma unroll
    for (int i = 0; i < 16; i++) {
        if (bkt[i] >= 0) {
            int loc = atomicAdd(&cnt2[bkt[i]], 1);
            tmp[(size_t)bkt[i] * BCAP + gb[bkt[i]] + loc] = val[i];
        }
    }
}

// ---- exclusive scan over nb coarse-bucket counts --------------------------
__global__ __launch_bounds__(256) void scanB_kernel(const int* __restrict__ coarse_fill,
        int* __restrict__ bucket_base, int nb, int N_, int etot, int* __restrict__ rowp)
{
    __shared__ int sd[256];
    int t = threadIdx.x;
    int c = (t < nb) ? coarse_fill[t] : 0;
    sd[t] = c;
    __syncthreads();
    for (int off = 1; off < 256; off <<= 1) {
        int y = (t >= off) ? sd[t - off] : 0;
        __syncthreads();
        sd[t] += y;
        __syncthreads();
    }
    if (t < nb) bucket_base[t] = sd[t] - c;   // exclusive
    if (t == 0) rowp[N_] = etot;              // safety (also set in passB)
}

// ---- pass B: per-bucket counting sort by dst&255; emits col + rowp --------
__global__ __launch_bounds__(1024) void passB_kernel(const unsigned int* __restrict__ tmp,
        const int* __restrict__ coarse_fill, const int* __restrict__ bucket_base,
        int* __restrict__ col, int* __restrict__ rowp, int N_)
{
    __shared__ int hist2[256];
    __shared__ int scn[256];
    __shared__ int off2[256];
    int b = blockIdx.x;
    int t = threadIdx.x;
    int n = coarse_fill[b];
    int base = bucket_base[b];
    const unsigned int* seg = tmp + (size_t)b * BCAP;

    if (t < 256) hist2[t] = 0;
    __syncthreads();
    for (int i = t; i < n; i += 1024) {
        unsigned int v = seg[i];
        atomicAdd(&hist2[(v >> 16) & 255], 1);
    }
    __syncthreads();
    int myc = (t < 256) ? hist2[t] : 0;
    if (t < 256) scn[t] = myc;
    __syncthreads();
    for (int off = 1; off < 256; off <<= 1) {
        int y = 0;
        if (t < 256 && t >= off) y = scn[t - off];
        __syncthreads();
        if (t < 256) scn[t] += y;
        __syncthreads();
    }
    int excl = 0;
    if (t < 256) {
        excl = scn[t] - myc;
        off2[t] = excl;
        int node = b * 256 + t;
        if (node <= N_) rowp[node] = base + excl;
    }
    __syncthreads();
    for (int i = t; i < n; i += 1024) {
        unsigned int v = seg[i];
        int bin = (v >> 16) & 255;
        int loc = atomicAdd(&off2[bin], 1);
        col[base + loc] = (int)(v & 0xFFFFu);
    }
}

// ---------------------------------------------------------------------------
// GEMM: Y[M,NOUT] = X[M,128] @ W[128,NOUT]. 4 rows x 4 cols per thread.
// ---------------------------------------------------------------------------
#define FMA4(A, S, WV) { A.x += (S)*(WV).x; A.y += (S)*(WV).y; A.z += (S)*(WV).z; A.w += (S)*(WV).w; }

template<int NOUT>
__global__ __launch_bounds__(256) void gemm_kernel(const float* __restrict__ X,
        const float* __restrict__ W, float* __restrict__ Y, int M)
{
    constexpr int CG = NOUT / 4;       // col groups per row
    constexpr int TR = (256 / CG) * 4; // rows per block
    int tid = threadIdx.x;
    int cx = tid % CG;
    int ry = tid / CG;
    int r0 = blockIdx.x * TR + ry * 4;
    int c0 = cx * 4;
    float4 acc0 = {0,0,0,0}, acc1 = {0,0,0,0}, acc2 = {0,0,0,0}, acc3 = {0,0,0,0};
    int r[4];
    #pragma unroll
    for (int i = 0; i < 4; i++) { r[i] = r0 + i; if (r[i] > M - 1) r[i] = M - 1; }
    for (int k = 0; k < 128; k += 4) {
        float4 x0 = *(const float4*)(X + (size_t)r[0] * 128 + k);
        float4 x1 = *(const float4*)(X + (size_t)r[1] * 128 + k);
        float4 x2 = *(const float4*)(X + (size_t)r[2] * 128 + k);
        float4 x3 = *(const float4*)(X + (size_t)r[3] * 128 + k);
        float4 w0 = *(const float4*)(W + (size_t)(k + 0) * NOUT + c0);
        float4 w1 = *(const float4*)(W + (size_t)(k + 1) * NOUT + c0);
        float4 w2 = *(const float4*)(W + (size_t)(k + 2) * NOUT + c0);
        float4 w3 = *(const float4*)(W + (size_t)(k + 3) * NOUT + c0);
        FMA4(acc0, x0.x, w0) FMA4(acc0, x0.y, w1) FMA4(acc0, x0.z, w2) FMA4(acc0, x0.w, w3)
        FMA4(acc1, x1.x, w0) FMA4(acc1, x1.y, w1) FMA4(acc1, x1.z, w2) FMA4(acc1, x1.w, w3)
        FMA4(acc2, x2.x, w0) FMA4(acc2, x2.y, w1) FMA4(acc2, x2.z, w2) FMA4(acc2, x2.w, w3)
        FMA4(acc3, x3.x, w0) FMA4(acc3, x3.y, w1) FMA4(acc3, x3.z, w2) FMA4(acc3, x3.w, w3)
    }
    if (r0 + 0 < M) *(float4*)(Y + (size_t)(r0 + 0) * NOUT + c0) = acc0;
    if (r0 + 1 < M) *(float4*)(Y + (size_t)(r0 + 1) * NOUT + c0) = acc1;
    if (r0 + 2 < M) *(float4*)(Y + (size_t)(r0 + 2) * NOUT + c0) = acc2;
    if (r0 + 3 < M) *(float4*)(Y + (size_t)(r0 + 3) * NOUT + c0) = acc3;
}

// ---------------------------------------------------------------------------
// Per-node attention dot products. One wave per node.
// ---------------------------------------------------------------------------
template<int H, int C>
__global__ __launch_bounds__(256) void attn_kernel(const float* __restrict__ Hf,
        const float* __restrict__ att_s, const float* __restrict__ att_d,
        float* __restrict__ as_, float* __restrict__ ad_, int M)
{
    constexpr int D = H * C, VPL = D / 64, GRP = C / VPL;
    int wave = threadIdx.x >> 6, lane = threadIdx.x & 63;
    int node = blockIdx.x * 4 + wave;
    if (node >= M) return;
    float ps = 0.f, pd = 0.f;
    #pragma unroll
    for (int v = 0; v < VPL; v++) {
        int ch = lane * VPL + v;
        float hv = Hf[(size_t)node * D + ch];
        ps += hv * att_s[ch];
        pd += hv * att_d[ch];
    }
    #pragma unroll
    for (int off = GRP / 2; off >= 1; off >>= 1) {
        ps += __shfl_xor(ps, off);
        pd += __shfl_xor(pd, off);
    }
    if ((lane & (GRP - 1)) == 0) {
        int h = lane / GRP;
        as_[node * H + h] = ps;
        ad_[node * H + h] = pd;
    }
}

// ---------------------------------------------------------------------------
// Segment softmax + aggregate, one wave per destination node.
// ---------------------------------------------------------------------------
template<int H, int C, bool ELU>
__global__ __launch_bounds__(256) void aggregate_kernel(
        const int* __restrict__ row_ptr, const int* __restrict__ col_src,
        const float* __restrict__ Hf, const float* __restrict__ asv,
        const float* __restrict__ adv, const float* __restrict__ bias,
        float* __restrict__ out, int nnodes)
{
    constexpr int D = H * C;
    constexpr int LPE = D / 4;     // lanes per edge (32 or 16)
    constexpr int EPI = 64 / LPE;  // edges per iteration (2 or 4)
    int wave = threadIdx.x >> 6, lane = threadIdx.x & 63;
    int node = blockIdx.x * 4 + wave;
    if (node >= nnodes) return;
    int start = row_ptr[node];
    int deg   = row_ptr[node + 1] - start;
    int li  = lane & (LPE - 1);
    int sub = lane / LPE;
    int my_head = (li * 4) / C;

    float adh[H];
    #pragma unroll
    for (int h = 0; h < H; h++) adh[h] = adv[node * H + h];

    // ---- pass A: segment max per head ----
    float m[H];
    #pragma unroll
    for (int h = 0; h < H; h++) m[h] = -3.0e38f;
    for (int c0 = 0; c0 < deg; c0 += 64) {
        int idx = c0 + lane;
        float e[H];
        if (idx < deg) {
            int s = col_src[start + idx];
            if constexpr (H == 4) {
                float4 av = *(const float4*)(asv + (size_t)s * 4);
                float t0 = av.x + adh[0], t1 = av.y + adh[1];
                float t2 = av.z + adh[2], t3 = av.w + adh[3];
                e[0] = fmaxf(t0, 0.2f * t0); e[1] = fmaxf(t1, 0.2f * t1);
                e[2] = fmaxf(t2, 0.2f * t2); e[3] = fmaxf(t3, 0.2f * t3);
            } else {
                #pragma unroll
                for (int h = 0; h < H; h++) {
                    float t = asv[(size_t)s * H + h] + adh[h];
                    e[h] = fmaxf(t, 0.2f * t);
                }
            }
        } else {
            #pragma unroll
            for (int h = 0; h < H; h++) e[h] = -3.0e38f;
        }
        #pragma unroll
        for (int h = 0; h < H; h++) {
            float v = e[h];
            #pragma unroll
            for (int off = 32; off >= 1; off >>= 1)
                v = fmaxf(v, __shfl_xor(v, off));
            m[h] = fmaxf(m[h], v);
        }
    }

    // ---- pass B: exp, sum, weighted accumulate ----
    float4 acc = {0.f, 0.f, 0.f, 0.f};
    float sacc = 0.f;
    for (int c0 = 0; c0 < deg; c0 += 64) {
        int cnt = deg - c0; if (cnt > 64) cnt = 64;
        int idx = c0 + lane;
        int svec = 0;
        float exv[H];
        #pragma unroll
        for (int h = 0; h < H; h++) exv[h] = 0.f;
        if (idx < deg) {
            svec = col_src[start + idx];
            if constexpr (H == 4) {
                float4 av = *(const float4*)(asv + (size_t)svec * 4);
                float t0 = av.x + adh[0], t1 = av.y + adh[1];
                float t2 = av.z + adh[2], t3 = av.w + adh[3];
                t0 = fmaxf(t0, 0.2f * t0); t1 = fmaxf(t1, 0.2f * t1);
                t2 = fmaxf(t2, 0.2f * t2); t3 = fmaxf(t3, 0.2f * t3);
                exv[0] = __expf(t0 - m[0]); exv[1] = __expf(t1 - m[1]);
                exv[2] = __expf(t2 - m[2]); exv[3] = __expf(t3 - m[3]);
            } else {
                #pragma unroll
                for (int h = 0; h < H; h++) {
                    float t = asv[(size_t)svec * H + h] + adh[h];
                    t = fmaxf(t, 0.2f * t);
                    exv[h] = __expf(t - m[h]);
                }
            }
        }
        for (int j = 0; j < cnt; j += EPI) {
            int el = j + sub;
            bool valid = (el < cnt);
            if (el > cnt - 1) el = cnt - 1;
            int sj = __shfl(svec, el);
            float exj;
            if constexpr (H == 4) {
                float v0 = __shfl(exv[0], el), v1 = __shfl(exv[1], el);
                float v2 = __shfl(exv[2], el), v3 = __shfl(exv[3], el);
                exj = (my_head == 0) ? v0 : ((my_head == 1) ? v1 : ((my_head == 2) ? v2 : v3));
            } else {
                exj = __shfl(exv[0], el);
            }
            if (!valid) exj = 0.f;
            sacc += exj;
            const float4 hv = *(const float4*)(Hf + (size_t)sj * D + li * 4);
            acc.x += exj * hv.x; acc.y += exj * hv.y;
            acc.z += exj * hv.z; acc.w += exj * hv.w;
        }
    }

    #pragma unroll
    for (int off = LPE; off < 64; off <<= 1) {
        sacc  += __shfl_xor(sacc, off);
        acc.x += __shfl_xor(acc.x, off);
        acc.y += __shfl_xor(acc.y, off);
        acc.z += __shfl_xor(acc.z, off);
        acc.w += __shfl_xor(acc.w, off);
    }
    if (sub == 0) {
        float inv = 1.f / (sacc + 1e-16f);
        int ch = li * 4;
        float4 r;
        r.x = acc.x * inv + bias[ch + 0];
        r.y = acc.y * inv + bias[ch + 1];
        r.z = acc.z * inv + bias[ch + 2];
        r.w = acc.w * inv + bias[ch + 3];
        if (ELU) {
            r.x = r.x > 0.f ? r.x : (__expf(r.x) - 1.f);
            r.y = r.y > 0.f ? r.y : (__expf(r.y) - 1.f);
            r.z = r.z > 0.f ? r.z : (__expf(r.z) - 1.f);
            r.w = r.w > 0.f ? r.w : (__expf(r.w) - 1.f);
        }
        *(float4*)(out + (size_t)node * D + ch) = r;
    }
}

// ---------------------------------------------------------------------------
extern "C" void kernel_launch(void* const* d_in, const int* in_sizes, int n_in,
                              void* d_out, int out_size, void* d_ws, size_t ws_size,
                              hipStream_t stream)
{
    const float* x        = (const float*)d_in[0];
    const int*   eidx     = (const int*)  d_in[1];
    const float* W1       = (const float*)d_in[2];
    const float* att_src1 = (const float*)d_in[3];
    const float* att_dst1 = (const float*)d_in[4];
    const float* bias1    = (const float*)d_in[5];
    const float* W2       = (const float*)d_in[6];
    const float* att_src2 = (const float*)d_in[7];
    const float* att_dst2 = (const float*)d_in[8];
    const float* bias2    = (const float*)d_in[9];
    float* out = (float*)d_out;

    const int N_ = in_sizes[0] / 128;
    const int E_ = in_sizes[1] / 2;
    const int ET = E_ + N_;
    const int NB = (N_ + 255) / 256;   // coarse buckets (196 for N=50000)

    char* p = (char*)d_ws;
    auto alloc = [&](size_t bytes) {
        void* r = (void*)p;
        p += ((bytes + 255) / 256) * 256;
        return r;
    };
    int*   rowp   = (int*)  alloc((size_t)(N_ + 1) * 4);
    int*   cfill  = (int*)  alloc((size_t)NB_BUCKETS * 4);
    int*   bbase  = (int*)  alloc((size_t)NB_BUCKETS * 4);
    int*   col    = (int*)  alloc((size_t)ET * 4);
    float* h1     = (float*)alloc((size_t)N_ * 128 * 4);
    float* hx     = (float*)alloc((size_t)N_ * 128 * 4);
    // tmp (bucket-sort staging, 12.85 MB) is dead before gemm2 writes h2 -> alias
    unsigned int* tmp = (unsigned int*)alloc((size_t)NB_BUCKETS * BCAP * 4);
    float* h2     = (float*)tmp;
    float* as1    = (float*)alloc((size_t)N_ * 4 * 4);
    float* ad1    = (float*)alloc((size_t)N_ * 4 * 4);
    float* as2    = (float*)alloc((size_t)N_ * 4);
    float* ad2    = (float*)alloc((size_t)N_ * 4);
    (void)ws_size; (void)n_in; (void)out_size;

    // ---- build dst-CSR via two-pass bucket sort ----
    hipMemsetAsync(cfill, 0, (size_t)NB_BUCKETS * 4, stream);
    splitA_kernel<<<(ET + 4095) / 4096, 256, 0, stream>>>(eidx, tmp, cfill, E_, ET, NB);
    scanB_kernel<<<1, 256, 0, stream>>>(cfill, bbase, NB, N_, ET, rowp);
    passB_kernel<<<NB, 1024, 0, stream>>>(tmp, cfill, bbase, col, rowp, N_);

    // ---- layer 1: H=4, C=32 ----
    gemm_kernel<128><<<(N_ + 31) / 32, 256, 0, stream>>>(x, W1, h1, N_);
    attn_kernel<4, 32><<<(N_ + 3) / 4, 256, 0, stream>>>(h1, att_src1, att_dst1, as1, ad1, N_);
    aggregate_kernel<4, 32, true><<<(N_ + 3) / 4, 256, 0, stream>>>(rowp, col, h1, as1, ad1, bias1, hx, N_);

    // ---- layer 2: H=1, C=64 ----
    gemm_kernel<64><<<(N_ + 63) / 64, 256, 0, stream>>>(hx, W2, h2, N_);
    attn_kernel<1, 64><<<(N_ + 3) / 4, 256, 0, stream>>>(h2, att_src2, att_dst2, as2, ad2, N_);
    aggregate_kernel<1, 64, false><<<(N_ + 3) / 4, 256, 0, stream>>>(rowp, col, h2, as2, ad2, bias2, out, N_);
}

// Round 3
// 353.424 us; speedup vs baseline: 1.6449x; 1.1556x over previous
//
#include <hip/hip_runtime.h>
#include <math.h>

// ---------------------------------------------------------------------------
// GAT 2-layer forward. N=50000, E=1.6M (+N self loops), F: 128 -> (4x32) -> 64.
// CSR build: two-pass bucket sort of packed (dst<<16|src) codes (R2).
// R3: layer-1 aggregate gathers a bf16 copy of h1 (halves dominant fabric
// traffic; logits stay fp32); both aggregates use fused online-softmax
// (single pass over edges instead of max-pass + exp-pass).
// ---------------------------------------------------------------------------

#define NB_BUCKETS 256   // max coarse buckets (dst>>8); actual used = ceil(N/256)
#define BCAP 16384       // fixed capacity per coarse bucket region (avg ~8448)

__device__ __forceinline__ float bflo(unsigned int u) { return __uint_as_float(u << 16); }
__device__ __forceinline__ float bfhi(unsigned int u) { return __uint_as_float(u & 0xFFFF0000u); }
__device__ __forceinline__ unsigned int f2bf_rne(float f) {
    unsigned int u = __float_as_uint(f);
    return (u + 0x7FFFu + ((u >> 16) & 1u)) >> 16;
}

// ---- pass A: block-aggregated split into coarse buckets by dst>>8 ----------
__global__ __launch_bounds__(256) void splitA_kernel(const int* __restrict__ eidx,
        unsigned int* __restrict__ tmp, int* __restrict__ coarse_fill,
        int E, int etot, int nb)
{
    __shared__ int hist[NB_BUCKETS];
    __shared__ int gb[NB_BUCKETS];
    __shared__ int cnt2[NB_BUCKETS];
    int t = threadIdx.x;
    if (t < nb) { hist[t] = 0; cnt2[t] = 0; }
    __syncthreads();

    unsigned int val[16];
    int bkt[16];
    int base = blockIdx.x * 4096;
    #pragma unroll
    for (int i = 0; i < 16; i++) {
        int idx = base + i * 256 + t;
        if (idx < etot) {
            unsigned int s, d;
            if (idx < E) { s = (unsigned int)eidx[idx]; d = (unsigned int)eidx[E + idx]; }
            else         { s = (unsigned int)(idx - E); d = s; }
            val[i] = (d << 16) | s;
            bkt[i] = (int)(d >> 8);
            atomicAdd(&hist[bkt[i]], 1);
        } else {
            bkt[i] = -1;
        }
    }
    __syncthreads();
    if (t < nb) {
        int n = hist[t];
        gb[t] = (n > 0) ? atomicAdd(&coarse_fill[t], n) : 0;
    }
    __syncthreads();
    #pragma unroll
    for (int i = 0; i < 16; i++) {
        if (bkt[i] >= 0) {
            int loc = atomicAdd(&cnt2[bkt[i]], 1);
            tmp[(size_t)bkt[i] * BCAP + gb[bkt[i]] + loc] = val[i];
        }
    }
}

// ---- exclusive scan over nb coarse-bucket counts --------------------------
__global__ __launch_bounds__(256) void scanB_kernel(const int* __restrict__ coarse_fill,
        int* __restrict__ bucket_base, int nb, int N_, int etot, int* __restrict__ rowp)
{
    __shared__ int sd[256];
    int t = threadIdx.x;
    int c = (t < nb) ? coarse_fill[t] : 0;
    sd[t] = c;
    __syncthreads();
    for (int off = 1; off < 256; off <<= 1) {
        int y = (t >= off) ? sd[t - off] : 0;
        __syncthreads();
        sd[t] += y;
        __syncthreads();
    }
    if (t < nb) bucket_base[t] = sd[t] - c;   // exclusive
    if (t == 0) rowp[N_] = etot;
}

// ---- pass B: per-bucket counting sort by dst&255; emits col + rowp --------
__global__ __launch_bounds__(1024) void passB_kernel(const unsigned int* __restrict__ tmp,
        const int* __restrict__ coarse_fill, const int* __restrict__ bucket_base,
        int* __restrict__ col, int* __restrict__ rowp, int N_)
{
    __shared__ int hist2[256];
    __shared__ int scn[256];
    __shared__ int off2[256];
    int b = blockIdx.x;
    int t = threadIdx.x;
    int n = coarse_fill[b];
    int base = bucket_base[b];
    const unsigned int* seg = tmp + (size_t)b * BCAP;

    if (t < 256) hist2[t] = 0;
    __syncthreads();
    for (int i = t; i < n; i += 1024) {
        unsigned int v = seg[i];
        atomicAdd(&hist2[(v >> 16) & 255], 1);
    }
    __syncthreads();
    int myc = (t < 256) ? hist2[t] : 0;
    if (t < 256) scn[t] = myc;
    __syncthreads();
    for (int off = 1; off < 256; off <<= 1) {
        int y = 0;
        if (t < 256 && t >= off) y = scn[t - off];
        __syncthreads();
        if (t < 256) scn[t] += y;
        __syncthreads();
    }
    if (t < 256) {
        int excl = scn[t] - myc;
        off2[t] = excl;
        int node = b * 256 + t;
        if (node <= N_) rowp[node] = base + excl;
    }
    __syncthreads();
    for (int i = t; i < n; i += 1024) {
        unsigned int v = seg[i];
        int bin = (v >> 16) & 255;
        int loc = atomicAdd(&off2[bin], 1);
        col[base + loc] = (int)(v & 0xFFFFu);
    }
}

// ---------------------------------------------------------------------------
// GEMM: Y[M,NOUT] = X[M,128] @ W[128,NOUT]. 4 rows x 4 cols per thread.
// ---------------------------------------------------------------------------
#define FMA4(A, S, WV) { A.x += (S)*(WV).x; A.y += (S)*(WV).y; A.z += (S)*(WV).z; A.w += (S)*(WV).w; }

template<int NOUT>
__global__ __launch_bounds__(256) void gemm_kernel(const float* __restrict__ X,
        const float* __restrict__ W, float* __restrict__ Y, int M)
{
    constexpr int CG = NOUT / 4;
    constexpr int TR = (256 / CG) * 4;
    int tid = threadIdx.x;
    int cx = tid % CG;
    int ry = tid / CG;
    int r0 = blockIdx.x * TR + ry * 4;
    int c0 = cx * 4;
    float4 acc0 = {0,0,0,0}, acc1 = {0,0,0,0}, acc2 = {0,0,0,0}, acc3 = {0,0,0,0};
    int r[4];
    #pragma unroll
    for (int i = 0; i < 4; i++) { r[i] = r0 + i; if (r[i] > M - 1) r[i] = M - 1; }
    for (int k = 0; k < 128; k += 4) {
        float4 x0 = *(const float4*)(X + (size_t)r[0] * 128 + k);
        float4 x1 = *(const float4*)(X + (size_t)r[1] * 128 + k);
        float4 x2 = *(const float4*)(X + (size_t)r[2] * 128 + k);
        float4 x3 = *(const float4*)(X + (size_t)r[3] * 128 + k);
        float4 w0 = *(const float4*)(W + (size_t)(k + 0) * NOUT + c0);
        float4 w1 = *(const float4*)(W + (size_t)(k + 1) * NOUT + c0);
        float4 w2 = *(const float4*)(W + (size_t)(k + 2) * NOUT + c0);
        float4 w3 = *(const float4*)(W + (size_t)(k + 3) * NOUT + c0);
        FMA4(acc0, x0.x, w0) FMA4(acc0, x0.y, w1) FMA4(acc0, x0.z, w2) FMA4(acc0, x0.w, w3)
        FMA4(acc1, x1.x, w0) FMA4(acc1, x1.y, w1) FMA4(acc1, x1.z, w2) FMA4(acc1, x1.w, w3)
        FMA4(acc2, x2.x, w0) FMA4(acc2, x2.y, w1) FMA4(acc2, x2.z, w2) FMA4(acc2, x2.w, w3)
        FMA4(acc3, x3.x, w0) FMA4(acc3, x3.y, w1) FMA4(acc3, x3.z, w2) FMA4(acc3, x3.w, w3)
    }
    if (r0 + 0 < M) *(float4*)(Y + (size_t)(r0 + 0) * NOUT + c0) = acc0;
    if (r0 + 1 < M) *(float4*)(Y + (size_t)(r0 + 1) * NOUT + c0) = acc1;
    if (r0 + 2 < M) *(float4*)(Y + (size_t)(r0 + 2) * NOUT + c0) = acc2;
    if (r0 + 3 < M) *(float4*)(Y + (size_t)(r0 + 3) * NOUT + c0) = acc3;
}

// ---------------------------------------------------------------------------
// Per-node attention dots; optionally emit bf16 copy of H (payload for agg1).
// One wave per node.
// ---------------------------------------------------------------------------
template<int H, int C, bool WRITEBF>
__global__ __launch_bounds__(256) void attn_kernel(const float* __restrict__ Hf,
        const float* __restrict__ att_s, const float* __restrict__ att_d,
        float* __restrict__ as_, float* __restrict__ ad_,
        unsigned int* __restrict__ hb, int M)
{
    constexpr int D = H * C, VPL = D / 64, GRP = C / VPL;
    int wave = threadIdx.x >> 6, lane = threadIdx.x & 63;
    int node = blockIdx.x * 4 + wave;
    if (node >= M) return;
    float ps = 0.f, pd = 0.f;
    float hv[VPL];
    #pragma unroll
    for (int v = 0; v < VPL; v++) {
        int ch = lane * VPL + v;
        hv[v] = Hf[(size_t)node * D + ch];
        ps += hv[v] * att_s[ch];
        pd += hv[v] * att_d[ch];
    }
    if constexpr (WRITEBF) {
        static_assert(!WRITEBF || VPL == 2, "pack assumes 2 ch/lane");
        unsigned int pk = f2bf_rne(hv[0]) | (f2bf_rne(hv[1]) << 16);
        hb[(size_t)node * (D / 2) + lane] = pk;
    }
    #pragma unroll
    for (int off = GRP / 2; off >= 1; off >>= 1) {
        ps += __shfl_xor(ps, off);
        pd += __shfl_xor(pd, off);
    }
    if ((lane & (GRP - 1)) == 0) {
        int h = lane / GRP;
        as_[node * H + h] = ps;
        ad_[node * H + h] = pd;
    }
}

// ---------------------------------------------------------------------------
// Fused online-softmax segment aggregate, one wave per destination node.
// Payload: bf16 (8 ch/lane) or fp32 (4 ch/lane); 16 lanes per edge either way.
// ---------------------------------------------------------------------------
template<int H, int C, bool ELU_, bool BF16P>
__global__ __launch_bounds__(256) void aggregate_fused(
        const int* __restrict__ row_ptr, const int* __restrict__ col_src,
        const void* __restrict__ payload, const float* __restrict__ asv,
        const float* __restrict__ adv, const float* __restrict__ bias,
        float* __restrict__ out, int nnodes)
{
    constexpr int D = H * C;
    constexpr int CPL = BF16P ? 8 : 4;   // channels per lane
    constexpr int LPE = D / CPL;         // lanes per edge (16 for both layers)
    constexpr int EPI = 64 / LPE;        // edges per inner iter (4)
    static_assert(LPE == 16, "layout assumes 16 lanes/edge");
    int wave = threadIdx.x >> 6, lane = threadIdx.x & 63;
    int node = blockIdx.x * 4 + wave;
    if (node >= nnodes) return;
    int start = row_ptr[node];
    int deg   = row_ptr[node + 1] - start;   // >= 1 (self loop)
    int li  = lane & 15;
    int sub = lane >> 4;
    int myh = (li * CPL) / C;

    float adh[H];
    #pragma unroll
    for (int h = 0; h < H; h++) adh[h] = adv[node * H + h];

    float m[H];
    #pragma unroll
    for (int h = 0; h < H; h++) m[h] = -3.0e38f;
    float acc[CPL];
    #pragma unroll
    for (int k = 0; k < CPL; k++) acc[k] = 0.f;
    float sacc = 0.f;

    for (int c0 = 0; c0 < deg; c0 += 64) {
        int cnt = deg - c0; if (cnt > 64) cnt = 64;
        int idx = c0 + lane;
        int svec = 0;
        float e[H];
        if (idx < deg) {
            svec = col_src[start + idx];
            if constexpr (H == 4) {
                float4 av = *(const float4*)(asv + (size_t)svec * 4);
                float t0 = av.x + adh[0], t1 = av.y + adh[1];
                float t2 = av.z + adh[2], t3 = av.w + adh[3];
                e[0] = fmaxf(t0, 0.2f * t0); e[1] = fmaxf(t1, 0.2f * t1);
                e[2] = fmaxf(t2, 0.2f * t2); e[3] = fmaxf(t3, 0.2f * t3);
            } else {
                float t = asv[svec] + adh[0];
                e[0] = fmaxf(t, 0.2f * t);
            }
        } else {
            #pragma unroll
            for (int h = 0; h < H; h++) e[h] = -3.0e38f;
        }
        // chunk max per head -> running max update + rescale
        float nm[H];
        #pragma unroll
        for (int h = 0; h < H; h++) {
            float v = e[h];
            #pragma unroll
            for (int off = 32; off >= 1; off >>= 1)
                v = fmaxf(v, __shfl_xor(v, off));
            nm[h] = fmaxf(m[h], v);
        }
        float sc = __expf(m[myh] - nm[myh]);  // first chunk: exp(-3e38-x) = 0
        sacc *= sc;
        #pragma unroll
        for (int k = 0; k < CPL; k++) acc[k] *= sc;
        #pragma unroll
        for (int h = 0; h < H; h++) m[h] = nm[h];

        float exv[H];
        #pragma unroll
        for (int h = 0; h < H; h++)
            exv[h] = (idx < deg) ? __expf(e[h] - m[h]) : 0.f;

        for (int j = 0; j < cnt; j += EPI) {
            int el = j + sub;
            bool valid = (el < cnt);
            if (el > cnt - 1) el = cnt - 1;
            int sj = __shfl(svec, el);
            float exj;
            if constexpr (H == 4) {
                float v0 = __shfl(exv[0], el), v1 = __shfl(exv[1], el);
                float v2 = __shfl(exv[2], el), v3 = __shfl(exv[3], el);
                float va = (myh & 1) ? v1 : v0;
                float vb = (myh & 1) ? v3 : v2;
                exj = (myh & 2) ? vb : va;
            } else {
                exj = __shfl(exv[0], el);
            }
            if (!valid) exj = 0.f;
            sacc += exj;
            if constexpr (BF16P) {
                const unsigned short* pay = (const unsigned short*)payload;
                uint4 hv = *(const uint4*)(pay + (size_t)sj * D + li * 8);
                acc[0] += exj * bflo(hv.x); acc[1] += exj * bfhi(hv.x);
                acc[2] += exj * bflo(hv.y); acc[3] += exj * bfhi(hv.y);
                acc[4] += exj * bflo(hv.z); acc[5] += exj * bfhi(hv.z);
                acc[6] += exj * bflo(hv.w); acc[7] += exj * bfhi(hv.w);
            } else {
                const float* pay = (const float*)payload;
                float4 hv = *(const float4*)(pay + (size_t)sj * D + li * 4);
                acc[0] += exj * hv.x; acc[1] += exj * hv.y;
                acc[2] += exj * hv.z; acc[3] += exj * hv.w;
            }
        }
    }

    #pragma unroll
    for (int off = 16; off < 64; off <<= 1) {
        sacc += __shfl_xor(sacc, off);
        #pragma unroll
        for (int k = 0; k < CPL; k++) acc[k] += __shfl_xor(acc[k], off);
    }
    if (sub == 0) {
        float inv = 1.f / (sacc + 1e-16f);
        int ch = li * CPL;
        float r[CPL];
        #pragma unroll
        for (int k = 0; k < CPL; k++) {
            r[k] = acc[k] * inv + bias[ch + k];
            if (ELU_) r[k] = r[k] > 0.f ? r[k] : (__expf(r[k]) - 1.f);
        }
        float4 w0 = { r[0], r[1], r[2], r[3] };
        *(float4*)(out + (size_t)node * D + ch) = w0;
        if constexpr (CPL == 8) {
            float4 w1 = { r[4], r[5], r[6], r[7] };
            *(float4*)(out + (size_t)node * D + ch + 4) = w1;
        }
    }
}

// ---------------------------------------------------------------------------
extern "C" void kernel_launch(void* const* d_in, const int* in_sizes, int n_in,
                              void* d_out, int out_size, void* d_ws, size_t ws_size,
                              hipStream_t stream)
{
    const float* x        = (const float*)d_in[0];
    const int*   eidx     = (const int*)  d_in[1];
    const float* W1       = (const float*)d_in[2];
    const float* att_src1 = (const float*)d_in[3];
    const float* att_dst1 = (const float*)d_in[4];
    const float* bias1    = (const float*)d_in[5];
    const float* W2       = (const float*)d_in[6];
    const float* att_src2 = (const float*)d_in[7];
    const float* att_dst2 = (const float*)d_in[8];
    const float* bias2    = (const float*)d_in[9];
    float* out = (float*)d_out;

    const int N_ = in_sizes[0] / 128;
    const int E_ = in_sizes[1] / 2;
    const int ET = E_ + N_;
    const int NB = (N_ + 255) / 256;

    char* p = (char*)d_ws;
    auto alloc = [&](size_t bytes) {
        void* r = (void*)p;
        p += ((bytes + 255) / 256) * 256;
        return r;
    };
    int*   rowp   = (int*)  alloc((size_t)(N_ + 1) * 4);
    int*   cfill  = (int*)  alloc((size_t)NB_BUCKETS * 4);
    int*   bbase  = (int*)  alloc((size_t)NB_BUCKETS * 4);
    int*   col    = (int*)  alloc((size_t)ET * 4);
    float* h1     = (float*)alloc((size_t)N_ * 128 * 4);
    float* hx     = (float*)alloc((size_t)N_ * 128 * 4);
    // 16.8 MB region triple-used over the kernel timeline (no overlap):
    //   tmp (CSR staging) -> h1b (bf16 payload for agg1) -> h2 (layer-2 feats)
    unsigned int* tmp = (unsigned int*)alloc((size_t)NB_BUCKETS * BCAP * 4);
    unsigned int* h1b = tmp;
    float*        h2  = (float*)tmp;
    float* as1    = (float*)alloc((size_t)N_ * 4 * 4);
    float* ad1    = (float*)alloc((size_t)N_ * 4 * 4);
    float* as2    = (float*)alloc((size_t)N_ * 4);
    float* ad2    = (float*)alloc((size_t)N_ * 4);
    (void)ws_size; (void)n_in; (void)out_size;

    // ---- build dst-CSR via two-pass bucket sort ----
    hipMemsetAsync(cfill, 0, (size_t)NB_BUCKETS * 4, stream);
    splitA_kernel<<<(ET + 4095) / 4096, 256, 0, stream>>>(eidx, tmp, cfill, E_, ET, NB);
    scanB_kernel<<<1, 256, 0, stream>>>(cfill, bbase, NB, N_, ET, rowp);
    passB_kernel<<<NB, 1024, 0, stream>>>(tmp, cfill, bbase, col, rowp, N_);

    // ---- layer 1: H=4, C=32, bf16 payload gather ----
    gemm_kernel<128><<<(N_ + 31) / 32, 256, 0, stream>>>(x, W1, h1, N_);
    attn_kernel<4, 32, true><<<(N_ + 3) / 4, 256, 0, stream>>>(h1, att_src1, att_dst1, as1, ad1, h1b, N_);
    aggregate_fused<4, 32, true, true><<<(N_ + 3) / 4, 256, 0, stream>>>(rowp, col, h1b, as1, ad1, bias1, hx, N_);

    // ---- layer 2: H=1, C=64, fp32 payload ----
    gemm_kernel<64><<<(N_ + 63) / 64, 256, 0, stream>>>(hx, W2, h2, N_);
    attn_kernel<1, 64, false><<<(N_ + 3) / 4, 256, 0, stream>>>(h2, att_src2, att_dst2, as2, ad2, nullptr, N_);
    aggregate_fused<1, 64, false, false><<<(N_ + 3) / 4, 256, 0, stream>>>(rowp, col, h2, as2, ad2, bias2, out, N_);
}

// Round 4
// 250.829 us; speedup vs baseline: 2.3177x; 1.4090x over previous
//
#include <hip/hip_runtime.h>
#include <hip/hip_fp16.h>
#include <math.h>

// ---------------------------------------------------------------------------
// GAT 2-layer forward. N=50000, E=1.6M (+N self loops), F: 128 -> (4x32) -> 64.
// R2: CSR via two-pass bucket sort of packed (dst<<16|src) codes.
// R4: GEMMs moved to fp16 MFMA (16x16x32) with attention dots + fp16 payload
// emission fused into the epilogue; pipeline is fp16 between all stages
// (x -> h1f16 -> hx16 -> h2f16 -> out fp32). Aggregates gather fp16 payloads.
// ---------------------------------------------------------------------------

#define NB_BUCKETS 256   // max coarse buckets (dst>>8); actual used = ceil(N/256)
#define BCAP 16384       // fixed capacity per coarse bucket region (avg ~8448)

typedef _Float16 half8 __attribute__((ext_vector_type(8)));
typedef float    floatx4 __attribute__((ext_vector_type(4)));

__device__ __forceinline__ unsigned short f2h_bits(float f) {
    return __half_as_ushort(__float2half(f));
}
__device__ __forceinline__ float h2f_lo(unsigned int u) {
    return __half2float(__ushort_as_half((unsigned short)(u & 0xFFFFu)));
}
__device__ __forceinline__ float h2f_hi(unsigned int u) {
    return __half2float(__ushort_as_half((unsigned short)(u >> 16)));
}

// ---- pass A: block-aggregated split into coarse buckets by dst>>8 ----------
__global__ __launch_bounds__(256) void splitA_kernel(const int* __restrict__ eidx,
        unsigned int* __restrict__ tmp, int* __restrict__ coarse_fill,
        int E, int etot, int nb)
{
    __shared__ int hist[NB_BUCKETS];
    __shared__ int gb[NB_BUCKETS];
    __shared__ int cnt2[NB_BUCKETS];
    int t = threadIdx.x;
    if (t < nb) { hist[t] = 0; cnt2[t] = 0; }
    __syncthreads();

    unsigned int val[16];
    int bkt[16];
    int base = blockIdx.x * 4096;
    #pragma unroll
    for (int i = 0; i < 16; i++) {
        int idx = base + i * 256 + t;
        if (idx < etot) {
            unsigned int s, d;
            if (idx < E) { s = (unsigned int)eidx[idx]; d = (unsigned int)eidx[E + idx]; }
            else         { s = (unsigned int)(idx - E); d = s; }
            val[i] = (d << 16) | s;
            bkt[i] = (int)(d >> 8);
            atomicAdd(&hist[bkt[i]], 1);
        } else {
            bkt[i] = -1;
        }
    }
    __syncthreads();
    if (t < nb) {
        int n = hist[t];
        gb[t] = (n > 0) ? atomicAdd(&coarse_fill[t], n) : 0;
    }
    __syncthreads();
    #pragma unroll
    for (int i = 0; i < 16; i++) {
        if (bkt[i] >= 0) {
            int loc = atomicAdd(&cnt2[bkt[i]], 1);
            tmp[(size_t)bkt[i] * BCAP + gb[bkt[i]] + loc] = val[i];
        }
    }
}

// ---- exclusive scan over nb coarse-bucket counts --------------------------
__global__ __launch_bounds__(256) void scanB_kernel(const int* __restrict__ coarse_fill,
        int* __restrict__ bucket_base, int nb, int N_, int etot, int* __restrict__ rowp)
{
    __shared__ int sd[256];
    int t = threadIdx.x;
    int c = (t < nb) ? coarse_fill[t] : 0;
    sd[t] = c;
    __syncthreads();
    for (int off = 1; off < 256; off <<= 1) {
        int y = (t >= off) ? sd[t - off] : 0;
        __syncthreads();
        sd[t] += y;
        __syncthreads();
    }
    if (t < nb) bucket_base[t] = sd[t] - c;   // exclusive
    if (t == 0) rowp[N_] = etot;
}

// ---- pass B: per-bucket counting sort by dst&255; emits col + rowp --------
__global__ __launch_bounds__(1024) void passB_kernel(const unsigned int* __restrict__ tmp,
        const int* __restrict__ coarse_fill, const int* __restrict__ bucket_base,
        int* __restrict__ col, int* __restrict__ rowp, int N_)
{
    __shared__ int hist2[256];
    __shared__ int scn[256];
    __shared__ int off2[256];
    int b = blockIdx.x;
    int t = threadIdx.x;
    int n = coarse_fill[b];
    int base = bucket_base[b];
    const unsigned int* seg = tmp + (size_t)b * BCAP;

    if (t < 256) hist2[t] = 0;
    __syncthreads();
    for (int i = t; i < n; i += 1024) {
        unsigned int v = seg[i];
        atomicAdd(&hist2[(v >> 16) & 255], 1);
    }
    __syncthreads();
    int myc = (t < 256) ? hist2[t] : 0;
    if (t < 256) scn[t] = myc;
    __syncthreads();
    for (int off = 1; off < 256; off <<= 1) {
        int y = 0;
        if (t < 256 && t >= off) y = scn[t - off];
        __syncthreads();
        if (t < 256) scn[t] += y;
        __syncthreads();
    }
    if (t < 256) {
        int excl = scn[t] - myc;
        off2[t] = excl;
        int node = b * 256 + t;
        if (node <= N_) rowp[node] = base + excl;
    }
    __syncthreads();
    for (int i = t; i < n; i += 1024) {
        unsigned int v = seg[i];
        int bin = (v >> 16) & 255;
        int loc = atomicAdd(&off2[bin], 1);
        col[base + loc] = (int)(v & 0xFFFFu);
    }
}

// ---------------------------------------------------------------------------
// Fused GEMM (fp16 MFMA) + attention dots + fp16 payload emission.
// Y[M, NT*16] = X[M,128] @ W[128, NT*16]; per-node per-head dots with att_s/d.
// Block = 256 thr = 4 waves; wave handles 16 rows x full N. W staged in LDS
// in B-fragment layout (lane holds B[k=quad*8+j][n=nt*16+col], 8 f16 = 16 B).
// A loaded straight from global in A-frag layout (A[m=lane&15][k=quad*8+j]).
// C/D layout: col=lane&15, row=quad*4+reg (verified, learn_hip m89/m91).
// ---------------------------------------------------------------------------
template<int NT, int H, bool AF16>
__global__ __launch_bounds__(256) void gemm_attn_kernel(
        const void* __restrict__ Xv, const float* __restrict__ W,
        const float* __restrict__ att_s, const float* __restrict__ att_d,
        unsigned short* __restrict__ Hf16, float* __restrict__ as_,
        float* __restrict__ ad_, int M)
{
    constexpr int D = NT * 16;      // output width
    constexpr int C = D / H;        // channels per head
    __shared__ _Float16 Bs[NT * 4 * 64 * 8];

    int t = threadIdx.x;
    // ---- stage W -> LDS in B-frag layout (one time per block) ----
    for (int idx = t; idx < 128 * D; idx += 256) {
        int k = idx / D;
        int n = idx - k * D;
        int nt = n >> 4, ks = k >> 5;
        int lane = (((k >> 3) & 3) << 4) | (n & 15);
        int j = k & 7;
        Bs[(((nt * 4 + ks) * 64 + lane) << 3) + j] = (_Float16)W[idx];
    }
    __syncthreads();

    int lane = t & 63;
    int wv = t >> 6;
    int quad = lane >> 4, colL = lane & 15;
    int row0 = blockIdx.x * 64 + wv * 16;

    // ---- A fragments: row = colL, k-octet = quad*8 ----
    int arow = row0 + colL; if (arow > M - 1) arow = M - 1;
    half8 afrag[4];
    if constexpr (AF16) {
        const unsigned short* Xh = (const unsigned short*)Xv;
        #pragma unroll
        for (int ks = 0; ks < 4; ks++)
            afrag[ks] = *(const half8*)(const void*)(Xh + (size_t)arow * 128 + ks * 32 + quad * 8);
    } else {
        const float* Xf = (const float*)Xv;
        #pragma unroll
        for (int ks = 0; ks < 4; ks++) {
            const float* pa = Xf + (size_t)arow * 128 + ks * 32 + quad * 8;
            float4 a0 = *(const float4*)pa;
            float4 a1 = *(const float4*)(pa + 4);
            half8 f;
            f[0] = (_Float16)a0.x; f[1] = (_Float16)a0.y;
            f[2] = (_Float16)a0.z; f[3] = (_Float16)a0.w;
            f[4] = (_Float16)a1.x; f[5] = (_Float16)a1.y;
            f[6] = (_Float16)a1.z; f[7] = (_Float16)a1.w;
            afrag[ks] = f;
        }
    }

    // ---- MFMA main: NT tiles x 4 k-steps ----
    floatx4 acc[NT];
    #pragma unroll
    for (int nt = 0; nt < NT; nt++) {
        floatx4 c = {0.f, 0.f, 0.f, 0.f};
        #pragma unroll
        for (int ks = 0; ks < 4; ks++) {
            half8 b = *(half8*)(void*)&Bs[(((nt * 4 + ks) * 64 + lane) << 3)];
            c = __builtin_amdgcn_mfma_f32_16x16x32_f16(afrag[ks], b, c, 0, 0, 0);
        }
        acc[nt] = c;
    }

    // ---- epilogue 1: per-head attention partials + 16-lane reduce ----
    float atts[NT], attd[NT];
    #pragma unroll
    for (int nt = 0; nt < NT; nt++) {
        int ch = nt * 16 + colL;
        atts[nt] = att_s[ch];
        attd[nt] = att_d[ch];
    }
    float ps[H][4], pd[H][4];
    #pragma unroll
    for (int h = 0; h < H; h++)
        #pragma unroll
        for (int r = 0; r < 4; r++) { ps[h][r] = 0.f; pd[h][r] = 0.f; }
    #pragma unroll
    for (int nt = 0; nt < NT; nt++) {
        constexpr int NTH = 16;  // dummy
        int h = (nt * 16) / C;   // head of this tile (compile-time per unroll)
        #pragma unroll
        for (int r = 0; r < 4; r++) {
            ps[h][r] += acc[nt][r] * atts[nt];
            pd[h][r] += acc[nt][r] * attd[nt];
        }
        (void)NTH;
    }
    #pragma unroll
    for (int h = 0; h < H; h++)
        #pragma unroll
        for (int r = 0; r < 4; r++)
            #pragma unroll
            for (int off = 1; off < 16; off <<= 1) {
                ps[h][r] += __shfl_xor(ps[h][r], off);
                pd[h][r] += __shfl_xor(pd[h][r], off);
            }
    if (colL < H) {
        #pragma unroll
        for (int r = 0; r < 4; r++) {
            int row = row0 + quad * 4 + r;
            if (row < M) {
                float vs, vd;
                if constexpr (H == 4) {
                    vs = colL == 0 ? ps[0][r] : colL == 1 ? ps[1][r] : colL == 2 ? ps[2][r] : ps[3][r];
                    vd = colL == 0 ? pd[0][r] : colL == 1 ? pd[1][r] : colL == 2 ? pd[2][r] : pd[3][r];
                } else {
                    vs = ps[0][r]; vd = pd[0][r];
                }
                as_[(size_t)row * H + colL] = vs;
                ad_[(size_t)row * H + colL] = vd;
            }
        }
    }

    // ---- epilogue 2: fp16 payload store ----
    #pragma unroll
    for (int r = 0; r < 4; r++) {
        int row = row0 + quad * 4 + r;
        if (row < M) {
            #pragma unroll
            for (int nt = 0; nt < NT; nt++)
                Hf16[(size_t)row * D + nt * 16 + colL] = f2h_bits(acc[nt][r]);
        }
    }
}

// ---------------------------------------------------------------------------
// Fused online-softmax segment aggregate, one wave per destination node.
// Payload always fp16 (8 ch/lane); LPE = D/8 lanes per edge (16 or 8).
// ---------------------------------------------------------------------------
template<int H, int C, bool ELU_, bool OUTF16>
__global__ __launch_bounds__(256) void aggregate_fused(
        const int* __restrict__ row_ptr, const int* __restrict__ col_src,
        const unsigned short* __restrict__ payload, const float* __restrict__ asv,
        const float* __restrict__ adv, const float* __restrict__ bias,
        void* __restrict__ outv, int nnodes)
{
    constexpr int D = H * C;
    constexpr int CPL = 8;            // channels per lane (uint4 of halves)
    constexpr int LPE = D / CPL;      // lanes per edge: 16 (L1) or 8 (L2)
    constexpr int EPI = 64 / LPE;     // edges per inner iter: 4 or 8
    int wave = threadIdx.x >> 6, lane = threadIdx.x & 63;
    int node = blockIdx.x * 4 + wave;
    if (node >= nnodes) return;
    int start = row_ptr[node];
    int deg   = row_ptr[node + 1] - start;   // >= 1 (self loop)
    int li  = lane & (LPE - 1);
    int sub = lane / LPE;
    int myh = (li * CPL) / C;

    float adh[H];
    #pragma unroll
    for (int h = 0; h < H; h++) adh[h] = adv[(size_t)node * H + h];

    float m[H];
    #pragma unroll
    for (int h = 0; h < H; h++) m[h] = -3.0e38f;
    float acc[CPL];
    #pragma unroll
    for (int k = 0; k < CPL; k++) acc[k] = 0.f;
    float sacc = 0.f;

    for (int c0 = 0; c0 < deg; c0 += 64) {
        int cnt = deg - c0; if (cnt > 64) cnt = 64;
        int idx = c0 + lane;
        int svec = 0;
        float e[H];
        if (idx < deg) {
            svec = col_src[start + idx];
            if constexpr (H == 4) {
                float4 av = *(const float4*)(asv + (size_t)svec * 4);
                float t0 = av.x + adh[0], t1 = av.y + adh[1];
                float t2 = av.z + adh[2], t3 = av.w + adh[3];
                e[0] = fmaxf(t0, 0.2f * t0); e[1] = fmaxf(t1, 0.2f * t1);
                e[2] = fmaxf(t2, 0.2f * t2); e[3] = fmaxf(t3, 0.2f * t3);
            } else {
                float tt = asv[svec] + adh[0];
                e[0] = fmaxf(tt, 0.2f * tt);
            }
        } else {
            #pragma unroll
            for (int h = 0; h < H; h++) e[h] = -3.0e38f;
        }
        // chunk max per head -> running max update + rescale
        float nm[H];
        #pragma unroll
        for (int h = 0; h < H; h++) {
            float v = e[h];
            #pragma unroll
            for (int off = 32; off >= 1; off >>= 1)
                v = fmaxf(v, __shfl_xor(v, off));
            nm[h] = fmaxf(m[h], v);
        }
        float sc = __expf(m[myh] - nm[myh]);  // first chunk: 0
        sacc *= sc;
        #pragma unroll
        for (int k = 0; k < CPL; k++) acc[k] *= sc;
        #pragma unroll
        for (int h = 0; h < H; h++) m[h] = nm[h];

        float exv[H];
        #pragma unroll
        for (int h = 0; h < H; h++)
            exv[h] = (idx < deg) ? __expf(e[h] - m[h]) : 0.f;

        for (int j = 0; j < cnt; j += EPI) {
            int el = j + sub;
            bool valid = (el < cnt);
            if (el > cnt - 1) el = cnt - 1;
            int sj = __shfl(svec, el);
            float exj;
            if constexpr (H == 4) {
                float v0 = __shfl(exv[0], el), v1 = __shfl(exv[1], el);
                float v2 = __shfl(exv[2], el), v3 = __shfl(exv[3], el);
                float va = (myh & 1) ? v1 : v0;
                float vb = (myh & 1) ? v3 : v2;
                exj = (myh & 2) ? vb : va;
            } else {
                exj = __shfl(exv[0], el);
            }
            if (!valid) exj = 0.f;
            sacc += exj;
            uint4 hv = *(const uint4*)(const void*)(payload + (size_t)sj * D + li * 8);
            acc[0] += exj * h2f_lo(hv.x); acc[1] += exj * h2f_hi(hv.x);
            acc[2] += exj * h2f_lo(hv.y); acc[3] += exj * h2f_hi(hv.y);
            acc[4] += exj * h2f_lo(hv.z); acc[5] += exj * h2f_hi(hv.z);
            acc[6] += exj * h2f_lo(hv.w); acc[7] += exj * h2f_hi(hv.w);
        }
    }

    #pragma unroll
    for (int off = LPE; off < 64; off <<= 1) {
        sacc += __shfl_xor(sacc, off);
        #pragma unroll
        for (int k = 0; k < CPL; k++) acc[k] += __shfl_xor(acc[k], off);
    }
    if (sub == 0) {
        float inv = 1.f / (sacc + 1e-16f);
        int ch = li * CPL;
        float r[CPL];
        #pragma unroll
        for (int k = 0; k < CPL; k++) {
            r[k] = acc[k] * inv + bias[ch + k];
            if (ELU_) r[k] = r[k] > 0.f ? r[k] : (__expf(r[k]) - 1.f);
        }
        if constexpr (OUTF16) {
            unsigned short* o = (unsigned short*)outv;
            unsigned int w0 = (unsigned int)f2h_bits(r[0]) | ((unsigned int)f2h_bits(r[1]) << 16);
            unsigned int w1 = (unsigned int)f2h_bits(r[2]) | ((unsigned int)f2h_bits(r[3]) << 16);
            unsigned int w2 = (unsigned int)f2h_bits(r[4]) | ((unsigned int)f2h_bits(r[5]) << 16);
            unsigned int w3 = (unsigned int)f2h_bits(r[6]) | ((unsigned int)f2h_bits(r[7]) << 16);
            uint4 q = { w0, w1, w2, w3 };
            *(uint4*)(void*)(o + (size_t)node * D + ch) = q;
        } else {
            float* o = (float*)outv;
            float4 w0 = { r[0], r[1], r[2], r[3] };
            float4 w1 = { r[4], r[5], r[6], r[7] };
            *(float4*)(o + (size_t)node * D + ch) = w0;
            *(float4*)(o + (size_t)node * D + ch + 4) = w1;
        }
    }
}

// ---------------------------------------------------------------------------
extern "C" void kernel_launch(void* const* d_in, const int* in_sizes, int n_in,
                              void* d_out, int out_size, void* d_ws, size_t ws_size,
                              hipStream_t stream)
{
    const float* x        = (const float*)d_in[0];
    const int*   eidx     = (const int*)  d_in[1];
    const float* W1       = (const float*)d_in[2];
    const float* att_src1 = (const float*)d_in[3];
    const float* att_dst1 = (const float*)d_in[4];
    const float* bias1    = (const float*)d_in[5];
    const float* W2       = (const float*)d_in[6];
    const float* att_src2 = (const float*)d_in[7];
    const float* att_dst2 = (const float*)d_in[8];
    const float* bias2    = (const float*)d_in[9];
    float* out = (float*)d_out;

    const int N_ = in_sizes[0] / 128;
    const int E_ = in_sizes[1] / 2;
    const int ET = E_ + N_;
    const int NB = (N_ + 255) / 256;

    char* p = (char*)d_ws;
    auto alloc = [&](size_t bytes) {
        void* r = (void*)p;
        p += ((bytes + 255) / 256) * 256;
        return r;
    };
    int* rowp  = (int*)alloc((size_t)(N_ + 1) * 4);
    int* cfill = (int*)alloc((size_t)NB_BUCKETS * 4);
    int* bbase = (int*)alloc((size_t)NB_BUCKETS * 4);
    int* colidx = (int*)alloc((size_t)ET * 4);
    // tmp (CSR staging, 16.8 MB) is dead after passB; h1f16 (12.8 MB) aliases it
    unsigned int*   tmp   = (unsigned int*)alloc((size_t)NB_BUCKETS * BCAP * 4);
    unsigned short* h1f16 = (unsigned short*)tmp;
    unsigned short* hx16  = (unsigned short*)alloc((size_t)N_ * 128 * 2);
    unsigned short* h2f16 = (unsigned short*)alloc((size_t)N_ * 64 * 2);
    float* as1 = (float*)alloc((size_t)N_ * 4 * 4);
    float* ad1 = (float*)alloc((size_t)N_ * 4 * 4);
    float* as2 = (float*)alloc((size_t)N_ * 4);
    float* ad2 = (float*)alloc((size_t)N_ * 4);
    (void)ws_size; (void)n_in; (void)out_size;

    // ---- build dst-CSR via two-pass bucket sort ----
    hipMemsetAsync(cfill, 0, (size_t)NB_BUCKETS * 4, stream);
    splitA_kernel<<<(ET + 4095) / 4096, 256, 0, stream>>>(eidx, tmp, cfill, E_, ET, NB);
    scanB_kernel<<<1, 256, 0, stream>>>(cfill, bbase, NB, N_, ET, rowp);
    passB_kernel<<<NB, 1024, 0, stream>>>(tmp, cfill, bbase, colidx, rowp, N_);

    // ---- layer 1: GEMM(fp16 MFMA)+attn fused; aggregate H=4,C=32 -> fp16 hx ----
    gemm_attn_kernel<8, 4, false><<<(N_ + 63) / 64, 256, 0, stream>>>(
        x, W1, att_src1, att_dst1, h1f16, as1, ad1, N_);
    aggregate_fused<4, 32, true, true><<<(N_ + 3) / 4, 256, 0, stream>>>(
        rowp, colidx, h1f16, as1, ad1, bias1, hx16, N_);

    // ---- layer 2: GEMM reads fp16 hx directly; aggregate H=1,C=64 -> fp32 out --
    gemm_attn_kernel<4, 1, true><<<(N_ + 63) / 64, 256, 0, stream>>>(
        hx16, W2, att_src2, att_dst2, h2f16, as2, ad2, N_);
    aggregate_fused<1, 64, false, false><<<(N_ + 3) / 4, 256, 0, stream>>>(
        rowp, colidx, h2f16, as2, ad2, bias2, out, N_);
}

// Round 5
// 245.454 us; speedup vs baseline: 2.3684x; 1.0219x over previous
//
#include <hip/hip_runtime.h>
#include <hip/hip_fp16.h>
#include <math.h>

// ---------------------------------------------------------------------------
// GAT 2-layer forward. N=50000, E=1.6M (+N self loops), F: 128 -> (4x32) -> 64.
// R2: CSR via two-pass bucket sort of packed (dst<<16|src) codes.
// R4: fp16-MFMA GEMMs with fused attention-dot epilogue; fp16 inter-stage.
// R5: aggregates exchange (exp, src-offset) through per-wave LDS (1 ds_read_b64
// per inner iter) instead of 5 bpermutes + selects; fma_mix-friendly inner FMA.
// ---------------------------------------------------------------------------

#define NB_BUCKETS 256   // max coarse buckets (dst>>8); actual used = ceil(N/256)
#define BCAP 16384       // fixed capacity per coarse bucket region (avg ~8448)

typedef _Float16 half8 __attribute__((ext_vector_type(8)));
typedef float    floatx4 __attribute__((ext_vector_type(4)));

__device__ __forceinline__ unsigned short f2h_bits(float f) {
    return __half_as_ushort(__float2half(f));
}
__device__ __forceinline__ float h2f_lo(unsigned int u) {
    return __half2float(__ushort_as_half((unsigned short)(u & 0xFFFFu)));
}
__device__ __forceinline__ float h2f_hi(unsigned int u) {
    return __half2float(__ushort_as_half((unsigned short)(u >> 16)));
}

// ---- pass A: block-aggregated split into coarse buckets by dst>>8 ----------
__global__ __launch_bounds__(256) void splitA_kernel(const int* __restrict__ eidx,
        unsigned int* __restrict__ tmp, int* __restrict__ coarse_fill,
        int E, int etot, int nb)
{
    __shared__ int hist[NB_BUCKETS];
    __shared__ int gb[NB_BUCKETS];
    __shared__ int cnt2[NB_BUCKETS];
    int t = threadIdx.x;
    if (t < nb) { hist[t] = 0; cnt2[t] = 0; }
    __syncthreads();

    unsigned int val[16];
    int bkt[16];
    int base = blockIdx.x * 4096;
    #pragma unroll
    for (int i = 0; i < 16; i++) {
        int idx = base + i * 256 + t;
        if (idx < etot) {
            unsigned int s, d;
            if (idx < E) { s = (unsigned int)eidx[idx]; d = (unsigned int)eidx[E + idx]; }
            else         { s = (unsigned int)(idx - E); d = s; }
            val[i] = (d << 16) | s;
            bkt[i] = (int)(d >> 8);
            atomicAdd(&hist[bkt[i]], 1);
        } else {
            bkt[i] = -1;
        }
    }
    __syncthreads();
    if (t < nb) {
        int n = hist[t];
        gb[t] = (n > 0) ? atomicAdd(&coarse_fill[t], n) : 0;
    }
    __syncthreads();
    #pragma unroll
    for (int i = 0; i < 16; i++) {
        if (bkt[i] >= 0) {
            int loc = atomicAdd(&cnt2[bkt[i]], 1);
            tmp[(size_t)bkt[i] * BCAP + gb[bkt[i]] + loc] = val[i];
        }
    }
}

// ---- exclusive scan over nb coarse-bucket counts --------------------------
__global__ __launch_bounds__(256) void scanB_kernel(const int* __restrict__ coarse_fill,
        int* __restrict__ bucket_base, int nb, int N_, int etot, int* __restrict__ rowp)
{
    __shared__ int sd[256];
    int t = threadIdx.x;
    int c = (t < nb) ? coarse_fill[t] : 0;
    sd[t] = c;
    __syncthreads();
    for (int off = 1; off < 256; off <<= 1) {
        int y = (t >= off) ? sd[t - off] : 0;
        __syncthreads();
        sd[t] += y;
        __syncthreads();
    }
    if (t < nb) bucket_base[t] = sd[t] - c;   // exclusive
    if (t == 0) rowp[N_] = etot;
}

// ---- pass B: per-bucket counting sort by dst&255; emits col + rowp --------
__global__ __launch_bounds__(1024) void passB_kernel(const unsigned int* __restrict__ tmp,
        const int* __restrict__ coarse_fill, const int* __restrict__ bucket_base,
        int* __restrict__ col, int* __restrict__ rowp, int N_)
{
    __shared__ int hist2[256];
    __shared__ int scn[256];
    __shared__ int off2[256];
    int b = blockIdx.x;
    int t = threadIdx.x;
    int n = coarse_fill[b];
    int base = bucket_base[b];
    const unsigned int* seg = tmp + (size_t)b * BCAP;

    if (t < 256) hist2[t] = 0;
    __syncthreads();
    for (int i = t; i < n; i += 1024) {
        unsigned int v = seg[i];
        atomicAdd(&hist2[(v >> 16) & 255], 1);
    }
    __syncthreads();
    int myc = (t < 256) ? hist2[t] : 0;
    if (t < 256) scn[t] = myc;
    __syncthreads();
    for (int off = 1; off < 256; off <<= 1) {
        int y = 0;
        if (t < 256 && t >= off) y = scn[t - off];
        __syncthreads();
        if (t < 256) scn[t] += y;
        __syncthreads();
    }
    if (t < 256) {
        int excl = scn[t] - myc;
        off2[t] = excl;
        int node = b * 256 + t;
        if (node <= N_) rowp[node] = base + excl;
    }
    __syncthreads();
    for (int i = t; i < n; i += 1024) {
        unsigned int v = seg[i];
        int bin = (v >> 16) & 255;
        int loc = atomicAdd(&off2[bin], 1);
        col[base + loc] = (int)(v & 0xFFFFu);
    }
}

// ---------------------------------------------------------------------------
// Fused GEMM (fp16 MFMA) + attention dots + fp16 payload emission.
// ---------------------------------------------------------------------------
template<int NT, int H, bool AF16>
__global__ __launch_bounds__(256) void gemm_attn_kernel(
        const void* __restrict__ Xv, const float* __restrict__ W,
        const float* __restrict__ att_s, const float* __restrict__ att_d,
        unsigned short* __restrict__ Hf16, float* __restrict__ as_,
        float* __restrict__ ad_, int M)
{
    constexpr int D = NT * 16;      // output width
    constexpr int C = D / H;        // channels per head
    __shared__ _Float16 Bs[NT * 4 * 64 * 8];

    int t = threadIdx.x;
    for (int idx = t; idx < 128 * D; idx += 256) {
        int k = idx / D;
        int n = idx - k * D;
        int nt = n >> 4, ks = k >> 5;
        int lane = (((k >> 3) & 3) << 4) | (n & 15);
        int j = k & 7;
        Bs[(((nt * 4 + ks) * 64 + lane) << 3) + j] = (_Float16)W[idx];
    }
    __syncthreads();

    int lane = t & 63;
    int wv = t >> 6;
    int quad = lane >> 4, colL = lane & 15;
    int row0 = blockIdx.x * 64 + wv * 16;

    int arow = row0 + colL; if (arow > M - 1) arow = M - 1;
    half8 afrag[4];
    if constexpr (AF16) {
        const unsigned short* Xh = (const unsigned short*)Xv;
        #pragma unroll
        for (int ks = 0; ks < 4; ks++)
            afrag[ks] = *(const half8*)(const void*)(Xh + (size_t)arow * 128 + ks * 32 + quad * 8);
    } else {
        const float* Xf = (const float*)Xv;
        #pragma unroll
        for (int ks = 0; ks < 4; ks++) {
            const float* pa = Xf + (size_t)arow * 128 + ks * 32 + quad * 8;
            float4 a0 = *(const float4*)pa;
            float4 a1 = *(const float4*)(pa + 4);
            half8 f;
            f[0] = (_Float16)a0.x; f[1] = (_Float16)a0.y;
            f[2] = (_Float16)a0.z; f[3] = (_Float16)a0.w;
            f[4] = (_Float16)a1.x; f[5] = (_Float16)a1.y;
            f[6] = (_Float16)a1.z; f[7] = (_Float16)a1.w;
            afrag[ks] = f;
        }
    }

    floatx4 acc[NT];
    #pragma unroll
    for (int nt = 0; nt < NT; nt++) {
        floatx4 c = {0.f, 0.f, 0.f, 0.f};
        #pragma unroll
        for (int ks = 0; ks < 4; ks++) {
            half8 b = *(half8*)(void*)&Bs[(((nt * 4 + ks) * 64 + lane) << 3)];
            c = __builtin_amdgcn_mfma_f32_16x16x32_f16(afrag[ks], b, c, 0, 0, 0);
        }
        acc[nt] = c;
    }

    float atts[NT], attd[NT];
    #pragma unroll
    for (int nt = 0; nt < NT; nt++) {
        int ch = nt * 16 + colL;
        atts[nt] = att_s[ch];
        attd[nt] = att_d[ch];
    }
    float ps[H][4], pd[H][4];
    #pragma unroll
    for (int h = 0; h < H; h++)
        #pragma unroll
        for (int r = 0; r < 4; r++) { ps[h][r] = 0.f; pd[h][r] = 0.f; }
    #pragma unroll
    for (int nt = 0; nt < NT; nt++) {
        int h = (nt * 16) / C;
        #pragma unroll
        for (int r = 0; r < 4; r++) {
            ps[h][r] += acc[nt][r] * atts[nt];
            pd[h][r] += acc[nt][r] * attd[nt];
        }
    }
    #pragma unroll
    for (int h = 0; h < H; h++)
        #pragma unroll
        for (int r = 0; r < 4; r++)
            #pragma unroll
            for (int off = 1; off < 16; off <<= 1) {
                ps[h][r] += __shfl_xor(ps[h][r], off);
                pd[h][r] += __shfl_xor(pd[h][r], off);
            }
    if (colL < H) {
        #pragma unroll
        for (int r = 0; r < 4; r++) {
            int row = row0 + quad * 4 + r;
            if (row < M) {
                float vs, vd;
                if constexpr (H == 4) {
                    vs = colL == 0 ? ps[0][r] : colL == 1 ? ps[1][r] : colL == 2 ? ps[2][r] : ps[3][r];
                    vd = colL == 0 ? pd[0][r] : colL == 1 ? pd[1][r] : colL == 2 ? pd[2][r] : pd[3][r];
                } else {
                    vs = ps[0][r]; vd = pd[0][r];
                }
                as_[(size_t)row * H + colL] = vs;
                ad_[(size_t)row * H + colL] = vd;
            }
        }
    }

    #pragma unroll
    for (int r = 0; r < 4; r++) {
        int row = row0 + quad * 4 + r;
        if (row < M) {
            #pragma unroll
            for (int nt = 0; nt < NT; nt++)
                Hf16[(size_t)row * D + nt * 16 + colL] = f2h_bits(acc[nt][r]);
        }
    }
}

// ---------------------------------------------------------------------------
// Fused online-softmax segment aggregate, one wave per destination node.
// R5: per-chunk (exp, byte-offset) exchange through per-wave LDS; inner loop
// is 1 ds_read_b64 + uint4 gather + 8 fma_mix per edge-slot. Invalid slots
// carry exj=0 (gather row 0 harmlessly) -> no masking in the hot loop.
// ---------------------------------------------------------------------------
template<int H, int C, bool ELU_, bool OUTF16>
__global__ __launch_bounds__(256) void aggregate_fused(
        const int* __restrict__ row_ptr, const int* __restrict__ col_src,
        const unsigned short* __restrict__ payload, const float* __restrict__ asv,
        const float* __restrict__ adv, const float* __restrict__ bias,
        void* __restrict__ outv, int nnodes)
{
    constexpr int D = H * C;
    constexpr int CPL = 8;            // channels per lane (uint4 of halves)
    constexpr int LPE = D / CPL;      // lanes per edge: 16 (L1) or 8 (L2)
    constexpr int EPI = 64 / LPE;     // edges per inner iter: 4 or 8
    // [wave][head][edge] exchange; pad edges dim 64->65 to decorrelate head banks
    __shared__ float2 exs[4][H][65];
    int wave = threadIdx.x >> 6, lane = threadIdx.x & 63;
    int node = blockIdx.x * 4 + wave;
    if (node >= nnodes) return;
    int start = row_ptr[node];
    int deg   = row_ptr[node + 1] - start;   // >= 1 (self loop)
    int li  = lane & (LPE - 1);
    int sub = lane / LPE;
    int myh = (li * CPL) / C;
    int lane_off = li * 16;                  // byte offset within a row

    float adh[H];
    #pragma unroll
    for (int h = 0; h < H; h++) adh[h] = adv[(size_t)node * H + h];

    float m[H];
    #pragma unroll
    for (int h = 0; h < H; h++) m[h] = -3.0e38f;
    float acc[CPL];
    #pragma unroll
    for (int k = 0; k < CPL; k++) acc[k] = 0.f;
    float sacc = 0.f;
    const char* pb = (const char*)payload;

    for (int c0 = 0; c0 < deg; c0 += 64) {
        int cnt = deg - c0; if (cnt > 64) cnt = 64;
        int idx = c0 + lane;
        int svec = 0;
        float e[H];
        if (idx < deg) {
            svec = col_src[start + idx];
            if constexpr (H == 4) {
                float4 av = *(const float4*)(asv + (size_t)svec * 4);
                float t0 = av.x + adh[0], t1 = av.y + adh[1];
                float t2 = av.z + adh[2], t3 = av.w + adh[3];
                e[0] = fmaxf(t0, 0.2f * t0); e[1] = fmaxf(t1, 0.2f * t1);
                e[2] = fmaxf(t2, 0.2f * t2); e[3] = fmaxf(t3, 0.2f * t3);
            } else {
                float tt = asv[svec] + adh[0];
                e[0] = fmaxf(tt, 0.2f * tt);
            }
        } else {
            #pragma unroll
            for (int h = 0; h < H; h++) e[h] = -3.0e38f;
        }
        // chunk max per head -> running max update + rescale
        float nm[H];
        #pragma unroll
        for (int h = 0; h < H; h++) {
            float v = e[h];
            #pragma unroll
            for (int off = 32; off >= 1; off >>= 1)
                v = fmaxf(v, __shfl_xor(v, off));
            nm[h] = fmaxf(m[h], v);
        }
        float sc = __expf(m[myh] - nm[myh]);  // first chunk: 0
        sacc *= sc;
        #pragma unroll
        for (int k = 0; k < CPL; k++) acc[k] *= sc;
        #pragma unroll
        for (int h = 0; h < H; h++) m[h] = nm[h];

        // producer: write {exp, row byte-offset} per head into wave-local LDS
        unsigned int boff = (unsigned int)svec * (unsigned int)(D * 2);
        float boff_f = __uint_as_float(boff);
        #pragma unroll
        for (int h = 0; h < H; h++) {
            float ex = (idx < deg) ? __expf(e[h] - m[h]) : 0.f;
            exs[wave][h][lane] = make_float2(ex, boff_f);
        }

        // consumer: EPI edges per iteration, no cross-lane ops, no masking
        int iters = (cnt + EPI - 1) / EPI;
        #pragma unroll 2
        for (int it = 0; it < iters; it++) {
            int el = it * EPI + sub;
            float2 v = exs[wave][myh][el];
            float exj = v.x;
            unsigned int off = __float_as_uint(v.y);
            uint4 hv = *(const uint4*)(const void*)(pb + off + lane_off);
            sacc += exj;
            acc[0] = fmaf(h2f_lo(hv.x), exj, acc[0]);
            acc[1] = fmaf(h2f_hi(hv.x), exj, acc[1]);
            acc[2] = fmaf(h2f_lo(hv.y), exj, acc[2]);
            acc[3] = fmaf(h2f_hi(hv.y), exj, acc[3]);
            acc[4] = fmaf(h2f_lo(hv.z), exj, acc[4]);
            acc[5] = fmaf(h2f_hi(hv.z), exj, acc[5]);
            acc[6] = fmaf(h2f_lo(hv.w), exj, acc[6]);
            acc[7] = fmaf(h2f_hi(hv.w), exj, acc[7]);
        }
    }

    #pragma unroll
    for (int off = LPE; off < 64; off <<= 1) {
        sacc += __shfl_xor(sacc, off);
        #pragma unroll
        for (int k = 0; k < CPL; k++) acc[k] += __shfl_xor(acc[k], off);
    }
    if (sub == 0) {
        float inv = 1.f / (sacc + 1e-16f);
        int ch = li * CPL;
        float r[CPL];
        #pragma unroll
        for (int k = 0; k < CPL; k++) {
            r[k] = acc[k] * inv + bias[ch + k];
            if (ELU_) r[k] = r[k] > 0.f ? r[k] : (__expf(r[k]) - 1.f);
        }
        if constexpr (OUTF16) {
            unsigned short* o = (unsigned short*)outv;
            unsigned int w0 = (unsigned int)f2h_bits(r[0]) | ((unsigned int)f2h_bits(r[1]) << 16);
            unsigned int w1 = (unsigned int)f2h_bits(r[2]) | ((unsigned int)f2h_bits(r[3]) << 16);
            unsigned int w2 = (unsigned int)f2h_bits(r[4]) | ((unsigned int)f2h_bits(r[5]) << 16);
            unsigned int w3 = (unsigned int)f2h_bits(r[6]) | ((unsigned int)f2h_bits(r[7]) << 16);
            uint4 q = { w0, w1, w2, w3 };
            *(uint4*)(void*)(o + (size_t)node * D + ch) = q;
        } else {
            float* o = (float*)outv;
            float4 w0 = { r[0], r[1], r[2], r[3] };
            float4 w1 = { r[4], r[5], r[6], r[7] };
            *(float4*)(o + (size_t)node * D + ch) = w0;
            *(float4*)(o + (size_t)node * D + ch + 4) = w1;
        }
    }
}

// ---------------------------------------------------------------------------
extern "C" void kernel_launch(void* const* d_in, const int* in_sizes, int n_in,
                              void* d_out, int out_size, void* d_ws, size_t ws_size,
                              hipStream_t stream)
{
    const float* x        = (const float*)d_in[0];
    const int*   eidx     = (const int*)  d_in[1];
    const float* W1       = (const float*)d_in[2];
    const float* att_src1 = (const float*)d_in[3];
    const float* att_dst1 = (const float*)d_in[4];
    const float* bias1    = (const float*)d_in[5];
    const float* W2       = (const float*)d_in[6];
    const float* att_src2 = (const float*)d_in[7];
    const float* att_dst2 = (const float*)d_in[8];
    const float* bias2    = (const float*)d_in[9];
    float* out = (float*)d_out;

    const int N_ = in_sizes[0] / 128;
    const int E_ = in_sizes[1] / 2;
    const int ET = E_ + N_;
    const int NB = (N_ + 255) / 256;

    char* p = (char*)d_ws;
    auto alloc = [&](size_t bytes) {
        void* r = (void*)p;
        p += ((bytes + 255) / 256) * 256;
        return r;
    };
    int* rowp  = (int*)alloc((size_t)(N_ + 1) * 4);
    int* cfill = (int*)alloc((size_t)NB_BUCKETS * 4);
    int* bbase = (int*)alloc((size_t)NB_BUCKETS * 4);
    int* colidx = (int*)alloc((size_t)ET * 4);
    // tmp (CSR staging, 16.8 MB) is dead after passB; h1f16 (12.8 MB) aliases it
    unsigned int*   tmp   = (unsigned int*)alloc((size_t)NB_BUCKETS * BCAP * 4);
    unsigned short* h1f16 = (unsigned short*)tmp;
    unsigned short* hx16  = (unsigned short*)alloc((size_t)N_ * 128 * 2);
    unsigned short* h2f16 = (unsigned short*)alloc((size_t)N_ * 64 * 2);
    float* as1 = (float*)alloc((size_t)N_ * 4 * 4);
    float* ad1 = (float*)alloc((size_t)N_ * 4 * 4);
    float* as2 = (float*)alloc((size_t)N_ * 4);
    float* ad2 = (float*)alloc((size_t)N_ * 4);
    (void)ws_size; (void)n_in; (void)out_size;

    // ---- build dst-CSR via two-pass bucket sort ----
    hipMemsetAsync(cfill, 0, (size_t)NB_BUCKETS * 4, stream);
    splitA_kernel<<<(ET + 4095) / 4096, 256, 0, stream>>>(eidx, tmp, cfill, E_, ET, NB);
    scanB_kernel<<<1, 256, 0, stream>>>(cfill, bbase, NB, N_, ET, rowp);
    passB_kernel<<<NB, 1024, 0, stream>>>(tmp, cfill, bbase, colidx, rowp, N_);

    // ---- layer 1: GEMM(fp16 MFMA)+attn fused; aggregate H=4,C=32 -> fp16 hx ----
    gemm_attn_kernel<8, 4, false><<<(N_ + 63) / 64, 256, 0, stream>>>(
        x, W1, att_src1, att_dst1, h1f16, as1, ad1, N_);
    aggregate_fused<4, 32, true, true><<<(N_ + 3) / 4, 256, 0, stream>>>(
        rowp, colidx, h1f16, as1, ad1, bias1, hx16, N_);

    // ---- layer 2: GEMM reads fp16 hx directly; aggregate H=1,C=64 -> fp32 out --
    gemm_attn_kernel<4, 1, true><<<(N_ + 63) / 64, 256, 0, stream>>>(
        hx16, W2, att_src2, att_dst2, h2f16, as2, ad2, N_);
    aggregate_fused<1, 64, false, false><<<(N_ + 3) / 4, 256, 0, stream>>>(
        rowp, colidx, h2f16, as2, ad2, bias2, out, N_);
}